// Round 9
// baseline (139.406 us; speedup 1.0000x reference)
//
#include <hip/hip_runtime.h>
#include <math.h>

#define B_ 4
#define T_ 512
#define D_ 64
#define EPS 1e-8f

__device__ __forceinline__ float wave_sum(float v) {
#pragma unroll
  for (int m = 1; m < 64; m <<= 1) v += __shfl_xor(v, m, 64);
  return v;
}
__device__ __forceinline__ float softplus_f(float x) {
  return fmaxf(x, 0.0f) + log1pf(expf(-fabsf(x)));
}

#define DOT4(ACC, A, Bv) \
  ACC = fmaf((A).x, (Bv).x, fmaf((A).y, (Bv).y, fmaf((A).z, (Bv).z, fmaf((A).w, (Bv).w, ACC))))

// ---- s = sqrt(double-normalized softplus simplex), row-major (coalesced) ----
__global__ __launch_bounds__(256) void proj_kernel(const float* __restrict__ x,
                                                   float* __restrict__ s) {
  int wave = threadIdx.x >> 6, lane = threadIdx.x & 63;
  int row = blockIdx.x * 4 + wave;  // (b,t) flat
  float sp = softplus_f(x[row * D_ + lane]);
  float s1 = wave_sum(sp);
  float p = sp / (s1 + EPS);
  p = fmaxf(p, EPS);
  float s2 = wave_sum(p);
  s[row * D_ + lane] = sqrtf(p / (s2 + EPS));
}

// Stage 512x64 f32 global -> LDS via global_load_lds DMA (no VGPR round-trip).
// LDS dest is LINEAR in lane order: byte addr = slot*16, slot = r*512 + tid
// (wave-uniform base + lane*16 — the required gload_lds pattern, m104/m173).
// Swizzle applied on the per-lane GLOBAL source address: physical (j,c4)
// holds logical (j, c4 ^ ((j>>2)&7)); readers use the same XOR (rule #21).
__device__ __forceinline__ void stage512_dma(const float* __restrict__ g,
                                             float* __restrict__ lds, int tid) {
#pragma unroll
  for (int r = 0; r < 16; ++r) {
    int slot = r * 512 + tid;
    int j = slot >> 4, c4 = slot & 15;
    const float* src = g + j * 64 + ((c4 ^ ((j >> 2) & 7)) << 2);
    __builtin_amdgcn_global_load_lds(
        (const __attribute__((address_space(1))) void*)src,
        (__attribute__((address_space(3))) void*)(lds + slot * 4), 16, 0, 0);
  }
}

// ---- fused iteration: logits + softmax + w@x + residual ----
// WRITE_S: emit next-iter s.  DO_COV: atomic-accumulate cov/mean/diag/kappa of
// the produced 8 rows into per-batch accumulators.  DO_ZERO: zero those
// accumulators for the NEXT dispatch (fence-free: dispatch boundary orders).
// Block: 8 query rows, 512 threads (8 waves). Grid (64, B).
template <int WRITE_S, int DO_COV, int DO_ZERO>
__global__ __launch_bounds__(512) void fiter_kernel(
    const float* __restrict__ s_g, const float* __restrict__ x_g,
    const float* __restrict__ rsp, float* __restrict__ xout,
    float* __restrict__ sout, float* __restrict__ covacc,
    float* __restrict__ meanacc, float* __restrict__ diagacc,
    float* __restrict__ kappacc) {
  int b = blockIdx.y, i0 = blockIdx.x * 8;
  int tid = threadIdx.x;
  int w = tid >> 6, lane = tid & 63;
  const float* sb = s_g + (size_t)b * (T_ * D_);
  const float* xb = x_g + (size_t)b * (T_ * D_);

  __shared__ __align__(16) float sx[512 * 64];   // s, then re-staged as x
  __shared__ __align__(16) float wlds[8 * 516];  // unnormalized exp weights
  __shared__ __align__(16) float redv[8 * 68];   // per-(row,d) PV partial
  __shared__ float redM[8][8];                   // rowmax partial [row][wave]
  __shared__ float redS[8][8];                   // exp-sum partial [row][wave]
  __shared__ float t8[8][68];                    // output rows (DO_COV)
  __shared__ float kred8[8];                     // row norms (DO_COV)

  if (DO_ZERO && blockIdx.x == 0) {
#pragma unroll
    for (int i = 0; i < 8; ++i) covacc[b * 4096 + i * 512 + tid] = 0.f;
    if (tid < 64) { meanacc[b * 64 + tid] = 0.f; diagacc[b * 64 + tid] = 0.f; }
    if (tid == 0) kappacc[b] = 0.f;
  }

  stage512_dma(sb, sx, tid);
  __syncthreads();  // drains vmcnt -> s resident

  // ---- phase L: logits S = -2*acos(clip(s_i . s_j)) for 8 rows x 64 cols ----
  int i4 = lane >> 4, j16 = lane & 15;
  int ia0 = i0 + 2 * i4;
  const float* A0 = sx + ia0 * 64;
  const float* A1 = A0 + 64;
  int mA0 = (ia0 >> 2) & 7, mA1 = ((ia0 + 1) >> 2) & 7;
  const float* Bp = sx + (w * 64 + 4 * j16) * 64;  // 4 consecutive j rows
  int mB = j16 & 7;

  float acc[2][4];
#pragma unroll
  for (int r = 0; r < 2; ++r)
#pragma unroll
    for (int c = 0; c < 4; ++c) acc[r][c] = 0.f;

#pragma unroll
  for (int d4 = 0; d4 < 16; ++d4) {
    float4 a0 = *(const float4*)(A0 + ((d4 ^ mA0) << 2));
    float4 a1 = *(const float4*)(A1 + ((d4 ^ mA1) << 2));
    int ob = (d4 ^ mB) << 2;
    float4 b0 = *(const float4*)(Bp + ob);
    float4 b1 = *(const float4*)(Bp + 64 + ob);
    float4 b2 = *(const float4*)(Bp + 128 + ob);
    float4 b3 = *(const float4*)(Bp + 192 + ob);
    DOT4(acc[0][0], a0, b0); DOT4(acc[0][1], a0, b1);
    DOT4(acc[0][2], a0, b2); DOT4(acc[0][3], a0, b3);
    DOT4(acc[1][0], a1, b0); DOT4(acc[1][1], a1, b1);
    DOT4(acc[1][2], a1, b2); DOT4(acc[1][3], a1, b3);
  }

  float S[2][4];
#pragma unroll
  for (int r = 0; r < 2; ++r)
#pragma unroll
    for (int c = 0; c < 4; ++c) {
      float inner = fminf(fmaxf(acc[r][c], -1.0f + 1e-6f), 1.0f - 1e-6f);
      S[r][c] = -2.0f * acosf(inner);
    }

  // per-wave rowmax over 64 cols (reduce across j16 = lane bits 0..3)
  float m0 = fmaxf(fmaxf(S[0][0], S[0][1]), fmaxf(S[0][2], S[0][3]));
  float m1 = fmaxf(fmaxf(S[1][0], S[1][1]), fmaxf(S[1][2], S[1][3]));
#pragma unroll
  for (int mm = 1; mm < 16; mm <<= 1) {
    m0 = fmaxf(m0, __shfl_xor(m0, mm, 64));
    m1 = fmaxf(m1, __shfl_xor(m1, mm, 64));
  }
  if (j16 == 0) { redM[2 * i4][w] = m0; redM[2 * i4 + 1][w] = m1; }
  __syncthreads();  // all waves done reading sx (s) + redM complete

  // re-stage x via DMA into the (now dead) s region; lands during softmax
  stage512_dma(xb, sx, tid);

  float M0 = redM[2 * i4][0], M1 = redM[2 * i4 + 1][0];
#pragma unroll
  for (int q = 1; q < 8; ++q) {
    M0 = fmaxf(M0, redM[2 * i4][q]);
    M1 = fmaxf(M1, redM[2 * i4 + 1][q]);
  }
  float e[2][4];
  float sl0 = 0.f, sl1 = 0.f;
#pragma unroll
  for (int c = 0; c < 4; ++c) {
    e[0][c] = __expf(S[0][c] - M0); sl0 += e[0][c];
    e[1][c] = __expf(S[1][c] - M1); sl1 += e[1][c];
  }
#pragma unroll
  for (int mm = 1; mm < 16; mm <<= 1) {
    sl0 += __shfl_xor(sl0, mm, 64);
    sl1 += __shfl_xor(sl1, mm, 64);
  }
  if (j16 == 0) { redS[2 * i4][w] = sl0; redS[2 * i4 + 1][w] = sl1; }
  int wb = w * 64 + 4 * j16;
#pragma unroll
  for (int r = 0; r < 2; ++r)
#pragma unroll
    for (int c = 0; c < 4; ++c) wlds[(2 * i4 + r) * 516 + wb + c] = e[r][c];
  __syncthreads();  // x DMA drained (vmcnt) + wlds/redS complete

  // ---- phase P: xa[i][d] = sum_j e[i][j] * x[j][d] ----
  int js = tid & 15, dg = (tid >> 4) & 15, ig = tid >> 8;
  int xcol = ((dg ^ (js & 7)) << 2);
  float pacc[4][4];
#pragma unroll
  for (int ii = 0; ii < 4; ++ii)
#pragma unroll
    for (int k = 0; k < 4; ++k) pacc[ii][k] = 0.f;

#pragma unroll 2
  for (int jj = 0; jj < 8; ++jj) {
    int jbase = jj * 64 + js * 4;
    const float* xr = sx + jbase * 64 + xcol;
    float4 x0 = *(const float4*)(xr);
    float4 x1 = *(const float4*)(xr + 64);
    float4 x2 = *(const float4*)(xr + 128);
    float4 x3 = *(const float4*)(xr + 192);
#pragma unroll
    for (int ii = 0; ii < 4; ++ii) {
      float4 wv = *(const float4*)(wlds + (4 * ig + ii) * 516 + jbase);
      pacc[ii][0] = fmaf(wv.x, x0.x, fmaf(wv.y, x1.x, fmaf(wv.z, x2.x, fmaf(wv.w, x3.x, pacc[ii][0]))));
      pacc[ii][1] = fmaf(wv.x, x0.y, fmaf(wv.y, x1.y, fmaf(wv.z, x2.y, fmaf(wv.w, x3.y, pacc[ii][1]))));
      pacc[ii][2] = fmaf(wv.x, x0.z, fmaf(wv.y, x1.z, fmaf(wv.z, x2.z, fmaf(wv.w, x3.z, pacc[ii][2]))));
      pacc[ii][3] = fmaf(wv.x, x0.w, fmaf(wv.y, x1.w, fmaf(wv.z, x2.w, fmaf(wv.w, x3.w, pacc[ii][3]))));
    }
  }
#pragma unroll
  for (int ii = 0; ii < 4; ++ii)
#pragma unroll
    for (int k = 0; k < 4; ++k) {
      float v = pacc[ii][k];
      v += __shfl_xor(v, 1, 64);
      v += __shfl_xor(v, 2, 64);
      v += __shfl_xor(v, 4, 64);
      v += __shfl_xor(v, 8, 64);
      pacc[ii][k] = v;
    }
  if (js == 0) {
#pragma unroll
    for (int ii = 0; ii < 4; ++ii)
      *(float4*)(redv + (4 * ig + ii) * 68 + (dg << 2)) =
          make_float4(pacc[ii][0], pacc[ii][1], pacc[ii][2], pacc[ii][3]);
  }
  __syncthreads();

  // ---- final: normalize, residual, write x (+ fused next-iter s / cov tile) ----
  {
    int row = w, d = lane;
    float ssum = 0.f;
#pragma unroll
    for (int q = 0; q < 8; ++q) ssum += redS[row][q];
    float xa = redv[row * 68 + d] / ssum;
    int ir = i0 + row;
    int mr = (ir >> 2) & 7;
    float xv = sx[ir * 64 + (((d >> 2) ^ mr) << 2) + (d & 3)];
    float c01 = 0.01f * rsp[0];
    float xn = 0.5f * (1.0f - c01) * xv + 0.5f * (1.0f + c01) * xa;
    size_t gi = ((size_t)(b * T_) + ir) * D_ + d;
    xout[gi] = xn;
    if (WRITE_S) {
      float sp = softplus_f(xn);
      float s1 = wave_sum(sp);
      float p = sp / (s1 + EPS);
      p = fmaxf(p, EPS);
      float s2 = wave_sum(p);
      sout[gi] = sqrtf(p / (s2 + EPS));
    }
    if (DO_COV) {
      t8[row][d] = xn;
      float ksq = wave_sum(xn * xn);
      if (lane == 0) kred8[row] = sqrtf(ksq);
    }
  }

  if (DO_COV) {
    __syncthreads();  // t8 + kred8 complete
    // cov partial: 512 threads = (dd 0..63) x (e8 0..7), 8 cells each, 8 rows
    int dd = tid >> 3, e8 = tid & 7;
    float ca[8];
#pragma unroll
    for (int k = 0; k < 8; ++k) ca[k] = 0.f;
#pragma unroll
    for (int r = 0; r < 8; ++r) {
      float xd = t8[r][dd];
      float4 v0 = *(const float4*)&t8[r][e8 * 8];
      float4 v1 = *(const float4*)&t8[r][e8 * 8 + 4];
      ca[0] = fmaf(xd, v0.x, ca[0]); ca[1] = fmaf(xd, v0.y, ca[1]);
      ca[2] = fmaf(xd, v0.z, ca[2]); ca[3] = fmaf(xd, v0.w, ca[3]);
      ca[4] = fmaf(xd, v1.x, ca[4]); ca[5] = fmaf(xd, v1.y, ca[5]);
      ca[6] = fmaf(xd, v1.z, ca[6]); ca[7] = fmaf(xd, v1.w, ca[7]);
    }
    float* cp = covacc + b * 4096 + dd * 64 + e8 * 8;
#pragma unroll
    for (int k = 0; k < 8; ++k) atomicAdd(cp + k, ca[k]);
    if (e8 == (dd >> 3)) atomicAdd(&diagacc[b * 64 + dd], ca[dd & 7]);
    if (tid < 64) {
      float ms = 0.f;
#pragma unroll
      for (int r = 0; r < 8; ++r) ms += t8[r][tid];
      atomicAdd(&meanacc[b * 64 + tid], ms);
    }
    if (tid == 0) {
      float ks = 0.f;
#pragma unroll
      for (int r = 0; r < 8; ++r) ks += kred8[r];
      atomicAdd(&kappacc[b], ks);
    }
  }
}

// ---- finalize: phi + kappa per batch from 16.5 KB accumulators ----
__global__ __launch_bounds__(256) void finalize_kernel(
    const float* __restrict__ covacc, const float* __restrict__ meanacc,
    const float* __restrict__ diagacc, const float* __restrict__ kappacc,
    float* __restrict__ out) {
  int b = blockIdx.x, tid = threadIdx.x;
  __shared__ float mu[64], var[64];
  __shared__ float phired[4];
  if (tid < 64) {
    float m = meanacc[b * 64 + tid] * (1.0f / 512.0f);
    mu[tid] = m;
    var[tid] = fmaxf(diagacc[b * 64 + tid] * (1.0f / 512.0f) - m * m, EPS);
  }
  __syncthreads();

  float psum = 0.f;
#pragma unroll
  for (int k = 0; k < 16; ++k) {
    int cell = k * 256 + tid;
    int dd = cell >> 6, e = cell & 63;
    float cov = covacc[b * 4096 + cell] * (1.0f / 512.0f) - mu[dd] * mu[e];
    if (e != dd) {
      float denom = fmaxf(sqrtf(var[dd] * var[e]), EPS);
      psum += fabsf(fminf(fmaxf(cov / denom, -1.0f), 1.0f));
    }
  }
  psum = wave_sum(psum);
  if ((tid & 63) == 0) phired[tid >> 6] = psum;
  __syncthreads();
  if (tid == 0) {
    out[B_ * T_ * D_ + b] = (phired[0] + phired[1] + phired[2] + phired[3]) *
                            (1.0f / 4096.0f);
    out[B_ * T_ * D_ + B_ + b] = kappacc[b] * (1.0f / 512.0f);
  }
}

extern "C" void kernel_launch(void* const* d_in, const int* in_sizes, int n_in,
                              void* d_out, int out_size, void* d_ws, size_t ws_size,
                              hipStream_t stream) {
  const float* x0 = (const float*)d_in[0];
  const float* rs = (const float*)d_in[1];
  float* out = (float*)d_out;
  float* s0     = (float*)d_ws;                // 131072 floats
  float* s1     = s0 + B_ * T_ * D_;           // 131072
  float* x1     = s1 + B_ * T_ * D_;           // 131072
  float* covacc = x1 + B_ * T_ * D_;           // 4*4096
  float* meanacc = covacc + B_ * 4096;         // 4*64
  float* diagacc = meanacc + B_ * 64;          // 4*64
  float* kappacc = diagacc + B_ * 64;          // 4

  dim3 fgrd(64, 4);
  proj_kernel<<<(B_ * T_) / 4, 256, 0, stream>>>(x0, s0);
  fiter_kernel<1, 0, 1><<<fgrd, 512, 0, stream>>>(s0, x0, rs, x1, s1, covacc,
                                                  meanacc, diagacc, kappacc);
  fiter_kernel<0, 1, 0><<<fgrd, 512, 0, stream>>>(s1, x1, rs, out, (float*)0,
                                                  covacc, meanacc, diagacc,
                                                  kappacc);
  finalize_kernel<<<B_, 256, 0, stream>>>(covacc, meanacc, diagacc, kappacc,
                                          out);
}

// Round 10
// 107.871 us; speedup vs baseline: 1.2923x; 1.2923x over previous
//
#include <hip/hip_runtime.h>
#include <math.h>

#define B_ 4
#define T_ 512
#define D_ 64
#define EPS 1e-8f

__device__ __forceinline__ float wave_sum(float v) {
#pragma unroll
  for (int m = 1; m < 64; m <<= 1) v += __shfl_xor(v, m, 64);
  return v;
}
__device__ __forceinline__ float softplus_f(float x) {
  return fmaxf(x, 0.0f) + log1pf(expf(-fabsf(x)));
}

#define DOT4(ACC, A, Bv) \
  ACC = fmaf((A).x, (Bv).x, fmaf((A).y, (Bv).y, fmaf((A).z, (Bv).z, fmaf((A).w, (Bv).w, ACC))))

// ---- s = sqrt(double-normalized softplus simplex), row-major (coalesced) ----
__global__ __launch_bounds__(256) void proj_kernel(const float* __restrict__ x,
                                                   float* __restrict__ s) {
  int wave = threadIdx.x >> 6, lane = threadIdx.x & 63;
  int row = blockIdx.x * 4 + wave;  // (b,t) flat
  float sp = softplus_f(x[row * D_ + lane]);
  float s1 = wave_sum(sp);
  float p = sp / (s1 + EPS);
  p = fmaxf(p, EPS);
  float s2 = wave_sum(p);
  s[row * D_ + lane] = sqrtf(p / (s2 + EPS));
}

// Stage 512x64 f32 (row-major, stride 64) global -> LDS with XOR swizzle.
// LDS physical (j, c4) holds logical (j, c4 ^ ((j>>2)&7)); reader of logical
// (j, d4) reads physical d4 ^ ((j>>2)&7).
__device__ __forceinline__ void stage512(const float* __restrict__ g,
                                         float* __restrict__ lds, int tid) {
#pragma unroll
  for (int h = 0; h < 2; ++h) {
    float4 v[8];
#pragma unroll
    for (int r = 0; r < 8; ++r) {
      int slot = (h * 8 + r) * 512 + tid;
      int j = slot >> 4, c4 = slot & 15;
      v[r] = *(const float4*)(g + j * 64 + ((c4 ^ ((j >> 2) & 7)) << 2));
    }
#pragma unroll
    for (int r = 0; r < 8; ++r) {
      int slot = (h * 8 + r) * 512 + tid;
      int j = slot >> 4, c4 = slot & 15;
      *(float4*)(lds + j * 64 + (c4 << 2)) = v[r];
    }
  }
}

// T14 async-stage split: issue all 16 swizzled-source loads early (hide HBM/L2
// latency under compute), write to LDS later once the region is dead.
__device__ __forceinline__ void stage_load(const float* __restrict__ g,
                                           float4* v, int tid) {
#pragma unroll
  for (int r = 0; r < 16; ++r) {
    int slot = r * 512 + tid;
    int j = slot >> 4, c4 = slot & 15;
    v[r] = *(const float4*)(g + j * 64 + ((c4 ^ ((j >> 2) & 7)) << 2));
  }
}
__device__ __forceinline__ void stage_write(const float4* v,
                                            float* __restrict__ lds, int tid) {
#pragma unroll
  for (int r = 0; r < 16; ++r) {
    int slot = r * 512 + tid;  // lds float-offset slot*4 == j*64 + c4*4
    *(float4*)(lds + slot * 4) = v[r];
  }
}

// ---- fused iteration: logits + softmax + w@x + residual ----
// WRITE_S: also emit next-iter s.  DO_COV: also emit per-block cov/mean/diag/
// kappa partials of the produced 8 output rows (fence-free p1 replacement),
// and zero the phi atomic accumulator for the NEXT dispatch (finalize).
// Block: 8 query rows, 512 threads (8 waves). Grid (64, B).
template <int WRITE_S, int DO_COV>
__global__ __launch_bounds__(512) void fiter_kernel(
    const float* __restrict__ s_g, const float* __restrict__ x_g,
    const float* __restrict__ rsp, float* __restrict__ xout,
    float* __restrict__ sout, float* __restrict__ covp,
    float* __restrict__ meanp, float* __restrict__ diagp,
    float* __restrict__ kappap) {
  int b = blockIdx.y, i0 = blockIdx.x * 8;
  int tid = threadIdx.x;
  int w = tid >> 6, lane = tid & 63;
  const float* sb = s_g + (size_t)b * (T_ * D_);
  const float* xb = x_g + (size_t)b * (T_ * D_);

  __shared__ __align__(16) float sx[512 * 64];   // s, then re-staged as x
  __shared__ __align__(16) float wlds[8 * 516];  // unnormalized exp weights
  __shared__ __align__(16) float redv[8 * 68];   // per-(row,d) PV partial
  __shared__ float redM[8][8];                   // rowmax partial [row][wave]
  __shared__ float redS[8][8];                   // exp-sum partial [row][wave]
  __shared__ float t8[8][68];                    // output rows (DO_COV)
  __shared__ float kred8[8];                     // row norms (DO_COV)

  if (DO_COV && blockIdx.x == 0 && tid == 0) xout[B_ * T_ * D_ + b] = 0.f;

  stage512(sb, sx, tid);
  __syncthreads();

  // T14: issue the x loads now — they complete under phase L's compute.
  float4 xreg[16];
  stage_load(xb, xreg, tid);

  // ---- phase L: logits S = -2*acos(clip(s_i . s_j)) for 8 rows x 64 cols ----
  int i4 = lane >> 4, j16 = lane & 15;
  int ia0 = i0 + 2 * i4;
  const float* A0 = sx + ia0 * 64;
  const float* A1 = A0 + 64;
  int mA0 = (ia0 >> 2) & 7, mA1 = ((ia0 + 1) >> 2) & 7;
  const float* Bp = sx + (w * 64 + 4 * j16) * 64;  // 4 consecutive j rows
  int mB = j16 & 7;

  float acc[2][4];
#pragma unroll
  for (int r = 0; r < 2; ++r)
#pragma unroll
    for (int c = 0; c < 4; ++c) acc[r][c] = 0.f;

#pragma unroll
  for (int d4 = 0; d4 < 16; ++d4) {
    float4 a0 = *(const float4*)(A0 + ((d4 ^ mA0) << 2));
    float4 a1 = *(const float4*)(A1 + ((d4 ^ mA1) << 2));
    int ob = (d4 ^ mB) << 2;
    float4 b0 = *(const float4*)(Bp + ob);
    float4 b1 = *(const float4*)(Bp + 64 + ob);
    float4 b2 = *(const float4*)(Bp + 128 + ob);
    float4 b3 = *(const float4*)(Bp + 192 + ob);
    DOT4(acc[0][0], a0, b0); DOT4(acc[0][1], a0, b1);
    DOT4(acc[0][2], a0, b2); DOT4(acc[0][3], a0, b3);
    DOT4(acc[1][0], a1, b0); DOT4(acc[1][1], a1, b1);
    DOT4(acc[1][2], a1, b2); DOT4(acc[1][3], a1, b3);
  }

  float S[2][4];
#pragma unroll
  for (int r = 0; r < 2; ++r)
#pragma unroll
    for (int c = 0; c < 4; ++c) {
      float inner = fminf(fmaxf(acc[r][c], -1.0f + 1e-6f), 1.0f - 1e-6f);
      S[r][c] = -2.0f * acosf(inner);
    }

  // per-wave rowmax over 64 cols (reduce across j16 = lane bits 0..3)
  float m0 = fmaxf(fmaxf(S[0][0], S[0][1]), fmaxf(S[0][2], S[0][3]));
  float m1 = fmaxf(fmaxf(S[1][0], S[1][1]), fmaxf(S[1][2], S[1][3]));
#pragma unroll
  for (int mm = 1; mm < 16; mm <<= 1) {
    m0 = fmaxf(m0, __shfl_xor(m0, mm, 64));
    m1 = fmaxf(m1, __shfl_xor(m1, mm, 64));
  }
  if (j16 == 0) { redM[2 * i4][w] = m0; redM[2 * i4 + 1][w] = m1; }
  __syncthreads();  // all waves done reading sx (s) + redM complete

  // write the (long-landed) x tile into the dead s region
  stage_write(xreg, sx, tid);

  float M0 = redM[2 * i4][0], M1 = redM[2 * i4 + 1][0];
#pragma unroll
  for (int q = 1; q < 8; ++q) {
    M0 = fmaxf(M0, redM[2 * i4][q]);
    M1 = fmaxf(M1, redM[2 * i4 + 1][q]);
  }
  float e[2][4];
  float sl0 = 0.f, sl1 = 0.f;
#pragma unroll
  for (int c = 0; c < 4; ++c) {
    e[0][c] = __expf(S[0][c] - M0); sl0 += e[0][c];
    e[1][c] = __expf(S[1][c] - M1); sl1 += e[1][c];
  }
#pragma unroll
  for (int mm = 1; mm < 16; mm <<= 1) {
    sl0 += __shfl_xor(sl0, mm, 64);
    sl1 += __shfl_xor(sl1, mm, 64);
  }
  if (j16 == 0) { redS[2 * i4][w] = sl0; redS[2 * i4 + 1][w] = sl1; }
  int wb = w * 64 + 4 * j16;
#pragma unroll
  for (int r = 0; r < 2; ++r)
    *(float4*)&wlds[(2 * i4 + r) * 516 + wb] =
        make_float4(e[r][0], e[r][1], e[r][2], e[r][3]);
  __syncthreads();  // x staged + wlds/redS complete

  // ---- phase P: xa[i][d] = sum_j e[i][j] * x[j][d] ----
  int js = tid & 15, dg = (tid >> 4) & 15, ig = tid >> 8;
  int xcol = ((dg ^ (js & 7)) << 2);
  float pacc[4][4];
#pragma unroll
  for (int ii = 0; ii < 4; ++ii)
#pragma unroll
    for (int k = 0; k < 4; ++k) pacc[ii][k] = 0.f;

#pragma unroll 2
  for (int jj = 0; jj < 8; ++jj) {
    int jbase = jj * 64 + js * 4;
    const float* xr = sx + jbase * 64 + xcol;
    float4 x0 = *(const float4*)(xr);
    float4 x1 = *(const float4*)(xr + 64);
    float4 x2 = *(const float4*)(xr + 128);
    float4 x3 = *(const float4*)(xr + 192);
#pragma unroll
    for (int ii = 0; ii < 4; ++ii) {
      float4 wv = *(const float4*)(wlds + (4 * ig + ii) * 516 + jbase);
      pacc[ii][0] = fmaf(wv.x, x0.x, fmaf(wv.y, x1.x, fmaf(wv.z, x2.x, fmaf(wv.w, x3.x, pacc[ii][0]))));
      pacc[ii][1] = fmaf(wv.x, x0.y, fmaf(wv.y, x1.y, fmaf(wv.z, x2.y, fmaf(wv.w, x3.y, pacc[ii][1]))));
      pacc[ii][2] = fmaf(wv.x, x0.z, fmaf(wv.y, x1.z, fmaf(wv.z, x2.z, fmaf(wv.w, x3.z, pacc[ii][2]))));
      pacc[ii][3] = fmaf(wv.x, x0.w, fmaf(wv.y, x1.w, fmaf(wv.z, x2.w, fmaf(wv.w, x3.w, pacc[ii][3]))));
    }
  }
#pragma unroll
  for (int ii = 0; ii < 4; ++ii)
#pragma unroll
    for (int k = 0; k < 4; ++k) {
      float v = pacc[ii][k];
      v += __shfl_xor(v, 1, 64);
      v += __shfl_xor(v, 2, 64);
      v += __shfl_xor(v, 4, 64);
      v += __shfl_xor(v, 8, 64);
      pacc[ii][k] = v;
    }
  if (js == 0) {
#pragma unroll
    for (int ii = 0; ii < 4; ++ii)
      *(float4*)(redv + (4 * ig + ii) * 68 + (dg << 2)) =
          make_float4(pacc[ii][0], pacc[ii][1], pacc[ii][2], pacc[ii][3]);
  }
  __syncthreads();

  // ---- final: normalize, residual, write x (+ fused next-iter s / cov tile) ----
  {
    int row = w, d = lane;
    float ssum = 0.f;
#pragma unroll
    for (int q = 0; q < 8; ++q) ssum += redS[row][q];
    float xa = redv[row * 68 + d] / ssum;
    int ir = i0 + row;
    int mr = (ir >> 2) & 7;
    float xv = sx[ir * 64 + (((d >> 2) ^ mr) << 2) + (d & 3)];
    float c01 = 0.01f * rsp[0];
    float xn = 0.5f * (1.0f - c01) * xv + 0.5f * (1.0f + c01) * xa;
    size_t gi = ((size_t)(b * T_) + ir) * D_ + d;
    xout[gi] = xn;
    if (WRITE_S) {
      float sp = softplus_f(xn);
      float s1 = wave_sum(sp);
      float p = sp / (s1 + EPS);
      p = fmaxf(p, EPS);
      float s2 = wave_sum(p);
      sout[gi] = sqrtf(p / (s2 + EPS));
    }
    if (DO_COV) {
      t8[row][d] = xn;
      float ksq = wave_sum(xn * xn);
      if (lane == 0) kred8[row] = sqrtf(ksq);
    }
  }

  if (DO_COV) {
    __syncthreads();  // t8 + kred8 complete
    int blk = b * 64 + blockIdx.x;
    // cov partial: 512 threads = (dd 0..63) x (e8 0..7), 8 cells each, 8 rows
    int dd = tid >> 3, e8 = tid & 7;
    float ca[8];
#pragma unroll
    for (int k = 0; k < 8; ++k) ca[k] = 0.f;
#pragma unroll
    for (int r = 0; r < 8; ++r) {
      float xd = t8[r][dd];
      float4 v0 = *(const float4*)&t8[r][e8 * 8];
      float4 v1 = *(const float4*)&t8[r][e8 * 8 + 4];
      ca[0] = fmaf(xd, v0.x, ca[0]); ca[1] = fmaf(xd, v0.y, ca[1]);
      ca[2] = fmaf(xd, v0.z, ca[2]); ca[3] = fmaf(xd, v0.w, ca[3]);
      ca[4] = fmaf(xd, v1.x, ca[4]); ca[5] = fmaf(xd, v1.y, ca[5]);
      ca[6] = fmaf(xd, v1.z, ca[6]); ca[7] = fmaf(xd, v1.w, ca[7]);
    }
    float* cp = covp + (size_t)blk * 4096 + dd * 64 + e8 * 8;
    *(float4*)(cp) = make_float4(ca[0], ca[1], ca[2], ca[3]);
    *(float4*)(cp + 4) = make_float4(ca[4], ca[5], ca[6], ca[7]);
    if (e8 == (dd >> 3)) diagp[blk * 64 + dd] = ca[dd & 7];  // raw sum x_d^2
    if (tid < 64) {
      float ms = 0.f;
#pragma unroll
      for (int r = 0; r < 8; ++r) ms += t8[r][tid];
      meanp[blk * 64 + tid] = ms;
    }
    if (tid == 0) {
      float ks = 0.f;
#pragma unroll
      for (int r = 0; r < 8; ++r) ks += kred8[r];
      kappap[blk] = ks;
    }
  }
}

// ---- finalize: separable phi over 16 slice-blocks per batch + kappa ----
__global__ __launch_bounds__(256) void finalize_kernel(
    const float* __restrict__ covp, const float* __restrict__ meanp,
    const float* __restrict__ diagp, const float* __restrict__ kappap,
    float* __restrict__ out) {
  int g = blockIdx.x, b = blockIdx.y, tid = threadIdx.x;
  __shared__ float mred[4][64], dred[4][64];
  __shared__ float mu[64], var[64];
  __shared__ float phired[4];
  {
    int d = tid & 63, q = tid >> 6;
    float ms = 0.f, ds = 0.f;
#pragma unroll
    for (int s = 0; s < 16; ++s) {
      int sl = q * 16 + s;
      ms += meanp[(b * 64 + sl) * 64 + d];
      ds += diagp[(b * 64 + sl) * 64 + d];
    }
    mred[q][d] = ms; dred[q][d] = ds;
  }
  __syncthreads();
  if (tid < 64) {
    float m = (mred[0][tid] + mred[1][tid] + mred[2][tid] + mred[3][tid]) *
              (1.0f / 512.0f);
    float dsum = dred[0][tid] + dred[1][tid] + dred[2][tid] + dred[3][tid];
    mu[tid] = m;
    var[tid] = fmaxf(dsum * (1.0f / 512.0f) - m * m, EPS);
  }
  __syncthreads();

  int cell = g * 256 + tid;
  int dd = cell >> 6, e = cell & 63;
  float csum = 0.f;
#pragma unroll 4
  for (int s = 0; s < 64; ++s) csum += covp[(size_t)(b * 64 + s) * 4096 + cell];
  float cov = csum * (1.0f / 512.0f) - mu[dd] * mu[e];
  float psum = 0.f;
  if (e != dd) {
    float denom = fmaxf(sqrtf(var[dd] * var[e]), EPS);
    psum = fabsf(fminf(fmaxf(cov / denom, -1.0f), 1.0f));
  }
  psum = wave_sum(psum);
  if ((tid & 63) == 0) phired[tid >> 6] = psum;
  __syncthreads();
  if (tid == 0) {
    atomicAdd(&out[B_ * T_ * D_ + b],
              (phired[0] + phired[1] + phired[2] + phired[3]) * (1.0f / 4096.0f));
    if (g == 0) {
      float ks = 0.f;
#pragma unroll
      for (int s = 0; s < 64; ++s) ks += kappap[b * 64 + s];
      out[B_ * T_ * D_ + B_ + b] = ks * (1.0f / 512.0f);
    }
  }
}

extern "C" void kernel_launch(void* const* d_in, const int* in_sizes, int n_in,
                              void* d_out, int out_size, void* d_ws, size_t ws_size,
                              hipStream_t stream) {
  const float* x0 = (const float*)d_in[0];
  const float* rs = (const float*)d_in[1];
  float* out = (float*)d_out;
  float* s0    = (float*)d_ws;                 // 131072 floats
  float* s1    = s0 + B_ * T_ * D_;            // 131072
  float* x1    = s1 + B_ * T_ * D_;            // 131072
  float* covp  = x1 + B_ * T_ * D_;            // 256*4096 = 1048576
  float* meanp = covp + 256 * 4096;            // 256*64
  float* diagp = meanp + 256 * 64;             // 256*64
  float* kappap = diagp + 256 * 64;            // 256

  dim3 fgrd(64, 4);
  proj_kernel<<<(B_ * T_) / 4, 256, 0, stream>>>(x0, s0);
  fiter_kernel<1, 0><<<fgrd, 512, 0, stream>>>(s0, x0, rs, x1, s1, (float*)0,
                                               (float*)0, (float*)0, (float*)0);
  fiter_kernel<0, 1><<<fgrd, 512, 0, stream>>>(s1, x1, rs, out, (float*)0,
                                               covp, meanp, diagp, kappap);
  finalize_kernel<<<dim3(16, B_), 256, 0, stream>>>(covp, meanp, diagp, kappap,
                                                    out);
}

// Round 11
// 92.391 us; speedup vs baseline: 1.5089x; 1.1675x over previous
//
#include <hip/hip_runtime.h>
#include <math.h>

#define B_ 4
#define T_ 512
#define D_ 64
#define EPS 1e-8f

__device__ __forceinline__ float wave_sum(float v) {
#pragma unroll
  for (int m = 1; m < 64; m <<= 1) v += __shfl_xor(v, m, 64);
  return v;
}
__device__ __forceinline__ float softplus_f(float x) {
  return fmaxf(x, 0.0f) + log1pf(expf(-fabsf(x)));
}

#define DOT4(ACC, A, Bv) \
  ACC = fmaf((A).x, (Bv).x, fmaf((A).y, (Bv).y, fmaf((A).z, (Bv).z, fmaf((A).w, (Bv).w, ACC))))

// ---- s = sqrt(double-normalized softplus simplex), row-major (coalesced) ----
__global__ __launch_bounds__(256) void proj_kernel(const float* __restrict__ x,
                                                   float* __restrict__ s) {
  int wave = threadIdx.x >> 6, lane = threadIdx.x & 63;
  int row = blockIdx.x * 4 + wave;  // (b,t) flat
  float sp = softplus_f(x[row * D_ + lane]);
  float s1 = wave_sum(sp);
  float p = sp / (s1 + EPS);
  p = fmaxf(p, EPS);
  float s2 = wave_sum(p);
  s[row * D_ + lane] = sqrtf(p / (s2 + EPS));
}

// Stage 512x64 f32 (row-major, stride 64) global -> LDS with XOR swizzle.
// LDS physical (j, c4) holds logical (j, c4 ^ ((j>>2)&7)); reader of logical
// (j, d4) reads physical d4 ^ ((j>>2)&7).
__device__ __forceinline__ void stage512(const float* __restrict__ g,
                                         float* __restrict__ lds, int tid) {
#pragma unroll
  for (int h = 0; h < 2; ++h) {
    float4 v[8];
#pragma unroll
    for (int r = 0; r < 8; ++r) {
      int slot = (h * 8 + r) * 512 + tid;
      int j = slot >> 4, c4 = slot & 15;
      v[r] = *(const float4*)(g + j * 64 + ((c4 ^ ((j >> 2) & 7)) << 2));
    }
#pragma unroll
    for (int r = 0; r < 8; ++r) {
      int slot = (h * 8 + r) * 512 + tid;
      int j = slot >> 4, c4 = slot & 15;
      *(float4*)(lds + j * 64 + (c4 << 2)) = v[r];
    }
  }
}

// ---- fused iteration: logits + softmax + w@x + residual ----
// WRITE_S: also emit next-iter s.  DO_COV: also emit per-block cov/mean/diag/
// kappa partials of the produced 8 output rows (fence-free p1 replacement),
// and zero the phi atomic accumulator for the NEXT dispatch (finalize).
// Block: 8 query rows, 512 threads (8 waves). Grid (64, B).
template <int WRITE_S, int DO_COV>
__global__ __launch_bounds__(512) void fiter_kernel(
    const float* __restrict__ s_g, const float* __restrict__ x_g,
    const float* __restrict__ rsp, float* __restrict__ xout,
    float* __restrict__ sout, float* __restrict__ covp,
    float* __restrict__ meanp, float* __restrict__ diagp,
    float* __restrict__ kappap) {
  int b = blockIdx.y, i0 = blockIdx.x * 8;
  int tid = threadIdx.x;
  int w = tid >> 6, lane = tid & 63;
  const float* sb = s_g + (size_t)b * (T_ * D_);
  const float* xb = x_g + (size_t)b * (T_ * D_);

  __shared__ __align__(16) float sx[512 * 64];   // s, then re-staged as x
  __shared__ __align__(16) float wlds[8 * 516];  // unnormalized exp weights
  __shared__ __align__(16) float redv[8 * 68];   // per-(row,d) PV partial
  __shared__ float redM[8][8];                   // rowmax partial [row][wave]
  __shared__ float redS[8][8];                   // exp-sum partial [row][wave]
  __shared__ float t8[8][68];                    // output rows (DO_COV)
  __shared__ float kred8[8];                     // row norms (DO_COV)

  if (DO_COV && blockIdx.x == 0 && tid == 0) xout[B_ * T_ * D_ + b] = 0.f;

  stage512(sb, sx, tid);
  __syncthreads();

  // ---- phase L: logits S = -2*acos(clip(s_i . s_j)) for 8 rows x 64 cols ----
  int i4 = lane >> 4, j16 = lane & 15;
  int ia0 = i0 + 2 * i4;
  const float* A0 = sx + ia0 * 64;
  const float* A1 = A0 + 64;
  int mA0 = (ia0 >> 2) & 7, mA1 = ((ia0 + 1) >> 2) & 7;
  const float* Bp = sx + (w * 64 + 4 * j16) * 64;  // 4 consecutive j rows
  int mB = j16 & 7;

  float acc[2][4];
#pragma unroll
  for (int r = 0; r < 2; ++r)
#pragma unroll
    for (int c = 0; c < 4; ++c) acc[r][c] = 0.f;

#pragma unroll
  for (int d4 = 0; d4 < 16; ++d4) {
    float4 a0 = *(const float4*)(A0 + ((d4 ^ mA0) << 2));
    float4 a1 = *(const float4*)(A1 + ((d4 ^ mA1) << 2));
    int ob = (d4 ^ mB) << 2;
    float4 b0 = *(const float4*)(Bp + ob);
    float4 b1 = *(const float4*)(Bp + 64 + ob);
    float4 b2 = *(const float4*)(Bp + 128 + ob);
    float4 b3 = *(const float4*)(Bp + 192 + ob);
    DOT4(acc[0][0], a0, b0); DOT4(acc[0][1], a0, b1);
    DOT4(acc[0][2], a0, b2); DOT4(acc[0][3], a0, b3);
    DOT4(acc[1][0], a1, b0); DOT4(acc[1][1], a1, b1);
    DOT4(acc[1][2], a1, b2); DOT4(acc[1][3], a1, b3);
  }

  float S[2][4];
#pragma unroll
  for (int r = 0; r < 2; ++r)
#pragma unroll
    for (int c = 0; c < 4; ++c) {
      float inner = fminf(fmaxf(acc[r][c], -1.0f + 1e-6f), 1.0f - 1e-6f);
      S[r][c] = -2.0f * acosf(inner);
    }

  // per-wave rowmax over 64 cols (reduce across j16 = lane bits 0..3)
  float m0 = fmaxf(fmaxf(S[0][0], S[0][1]), fmaxf(S[0][2], S[0][3]));
  float m1 = fmaxf(fmaxf(S[1][0], S[1][1]), fmaxf(S[1][2], S[1][3]));
#pragma unroll
  for (int mm = 1; mm < 16; mm <<= 1) {
    m0 = fmaxf(m0, __shfl_xor(m0, mm, 64));
    m1 = fmaxf(m1, __shfl_xor(m1, mm, 64));
  }
  if (j16 == 0) { redM[2 * i4][w] = m0; redM[2 * i4 + 1][w] = m1; }
  __syncthreads();  // all waves done reading sx (s) + redM complete

  // re-stage x into the (now dead) s region; latency overlaps softmax finish
  stage512(xb, sx, tid);

  float M0 = redM[2 * i4][0], M1 = redM[2 * i4 + 1][0];
#pragma unroll
  for (int q = 1; q < 8; ++q) {
    M0 = fmaxf(M0, redM[2 * i4][q]);
    M1 = fmaxf(M1, redM[2 * i4 + 1][q]);
  }
  float e[2][4];
  float sl0 = 0.f, sl1 = 0.f;
#pragma unroll
  for (int c = 0; c < 4; ++c) {
    e[0][c] = __expf(S[0][c] - M0); sl0 += e[0][c];
    e[1][c] = __expf(S[1][c] - M1); sl1 += e[1][c];
  }
#pragma unroll
  for (int mm = 1; mm < 16; mm <<= 1) {
    sl0 += __shfl_xor(sl0, mm, 64);
    sl1 += __shfl_xor(sl1, mm, 64);
  }
  if (j16 == 0) { redS[2 * i4][w] = sl0; redS[2 * i4 + 1][w] = sl1; }
  int wb = w * 64 + 4 * j16;
#pragma unroll
  for (int r = 0; r < 2; ++r)
#pragma unroll
    for (int c = 0; c < 4; ++c) wlds[(2 * i4 + r) * 516 + wb + c] = e[r][c];
  __syncthreads();  // x staged + wlds/redS complete

  // ---- phase P: xa[i][d] = sum_j e[i][j] * x[j][d] ----
  int js = tid & 15, dg = (tid >> 4) & 15, ig = tid >> 8;
  int xcol = ((dg ^ (js & 7)) << 2);
  float pacc[4][4];
#pragma unroll
  for (int ii = 0; ii < 4; ++ii)
#pragma unroll
    for (int k = 0; k < 4; ++k) pacc[ii][k] = 0.f;

#pragma unroll 2
  for (int jj = 0; jj < 8; ++jj) {
    int jbase = jj * 64 + js * 4;
    const float* xr = sx + jbase * 64 + xcol;
    float4 x0 = *(const float4*)(xr);
    float4 x1 = *(const float4*)(xr + 64);
    float4 x2 = *(const float4*)(xr + 128);
    float4 x3 = *(const float4*)(xr + 192);
#pragma unroll
    for (int ii = 0; ii < 4; ++ii) {
      float4 wv = *(const float4*)(wlds + (4 * ig + ii) * 516 + jbase);
      pacc[ii][0] = fmaf(wv.x, x0.x, fmaf(wv.y, x1.x, fmaf(wv.z, x2.x, fmaf(wv.w, x3.x, pacc[ii][0]))));
      pacc[ii][1] = fmaf(wv.x, x0.y, fmaf(wv.y, x1.y, fmaf(wv.z, x2.y, fmaf(wv.w, x3.y, pacc[ii][1]))));
      pacc[ii][2] = fmaf(wv.x, x0.z, fmaf(wv.y, x1.z, fmaf(wv.z, x2.z, fmaf(wv.w, x3.z, pacc[ii][2]))));
      pacc[ii][3] = fmaf(wv.x, x0.w, fmaf(wv.y, x1.w, fmaf(wv.z, x2.w, fmaf(wv.w, x3.w, pacc[ii][3]))));
    }
  }
#pragma unroll
  for (int ii = 0; ii < 4; ++ii)
#pragma unroll
    for (int k = 0; k < 4; ++k) {
      float v = pacc[ii][k];
      v += __shfl_xor(v, 1, 64);
      v += __shfl_xor(v, 2, 64);
      v += __shfl_xor(v, 4, 64);
      v += __shfl_xor(v, 8, 64);
      pacc[ii][k] = v;
    }
  if (js == 0) {
#pragma unroll
    for (int ii = 0; ii < 4; ++ii)
      *(float4*)(redv + (4 * ig + ii) * 68 + (dg << 2)) =
          make_float4(pacc[ii][0], pacc[ii][1], pacc[ii][2], pacc[ii][3]);
  }
  __syncthreads();

  // ---- final: normalize, residual, write x (+ fused next-iter s / cov tile) ----
  {
    int row = w, d = lane;
    float ssum = 0.f;
#pragma unroll
    for (int q = 0; q < 8; ++q) ssum += redS[row][q];
    float xa = redv[row * 68 + d] / ssum;
    int ir = i0 + row;
    int mr = (ir >> 2) & 7;
    float xv = sx[ir * 64 + (((d >> 2) ^ mr) << 2) + (d & 3)];
    float c01 = 0.01f * rsp[0];
    float xn = 0.5f * (1.0f - c01) * xv + 0.5f * (1.0f + c01) * xa;
    size_t gi = ((size_t)(b * T_) + ir) * D_ + d;
    xout[gi] = xn;
    if (WRITE_S) {
      float sp = softplus_f(xn);
      float s1 = wave_sum(sp);
      float p = sp / (s1 + EPS);
      p = fmaxf(p, EPS);
      float s2 = wave_sum(p);
      sout[gi] = sqrtf(p / (s2 + EPS));
    }
    if (DO_COV) {
      t8[row][d] = xn;
      float ksq = wave_sum(xn * xn);
      if (lane == 0) kred8[row] = sqrtf(ksq);
    }
  }

  if (DO_COV) {
    __syncthreads();  // t8 + kred8 complete
    int blk = b * 64 + blockIdx.x;
    // cov partial: 512 threads = (dd 0..63) x (e8 0..7), 8 cells each, 8 rows
    int dd = tid >> 3, e8 = tid & 7;
    float ca[8];
#pragma unroll
    for (int k = 0; k < 8; ++k) ca[k] = 0.f;
#pragma unroll
    for (int r = 0; r < 8; ++r) {
      float xd = t8[r][dd];
      float4 v0 = *(const float4*)&t8[r][e8 * 8];
      float4 v1 = *(const float4*)&t8[r][e8 * 8 + 4];
      ca[0] = fmaf(xd, v0.x, ca[0]); ca[1] = fmaf(xd, v0.y, ca[1]);
      ca[2] = fmaf(xd, v0.z, ca[2]); ca[3] = fmaf(xd, v0.w, ca[3]);
      ca[4] = fmaf(xd, v1.x, ca[4]); ca[5] = fmaf(xd, v1.y, ca[5]);
      ca[6] = fmaf(xd, v1.z, ca[6]); ca[7] = fmaf(xd, v1.w, ca[7]);
    }
    float* cp = covp + (size_t)blk * 4096 + dd * 64 + e8 * 8;
    *(float4*)(cp) = make_float4(ca[0], ca[1], ca[2], ca[3]);
    *(float4*)(cp + 4) = make_float4(ca[4], ca[5], ca[6], ca[7]);
    if (e8 == (dd >> 3)) diagp[blk * 64 + dd] = ca[dd & 7];  // raw sum x_d^2
    if (tid < 64) {
      float ms = 0.f;
#pragma unroll
      for (int r = 0; r < 8; ++r) ms += t8[r][tid];
      meanp[blk * 64 + tid] = ms;
    }
    if (tid == 0) {
      float ks = 0.f;
#pragma unroll
      for (int r = 0; r < 8; ++r) ks += kred8[r];
      kappap[blk] = ks;
    }
  }
}

// ---- finalize: separable phi over 16 slice-blocks per batch + kappa ----
__global__ __launch_bounds__(256) void finalize_kernel(
    const float* __restrict__ covp, const float* __restrict__ meanp,
    const float* __restrict__ diagp, const float* __restrict__ kappap,
    float* __restrict__ out) {
  int g = blockIdx.x, b = blockIdx.y, tid = threadIdx.x;
  __shared__ float mred[4][64], dred[4][64];
  __shared__ float mu[64], var[64];
  __shared__ float phired[4];
  {
    int d = tid & 63, q = tid >> 6;
    float ms = 0.f, ds = 0.f;
#pragma unroll
    for (int s = 0; s < 16; ++s) {
      int sl = q * 16 + s;
      ms += meanp[(b * 64 + sl) * 64 + d];
      ds += diagp[(b * 64 + sl) * 64 + d];
    }
    mred[q][d] = ms; dred[q][d] = ds;
  }
  __syncthreads();
  if (tid < 64) {
    float m = (mred[0][tid] + mred[1][tid] + mred[2][tid] + mred[3][tid]) *
              (1.0f / 512.0f);
    float dsum = dred[0][tid] + dred[1][tid] + dred[2][tid] + dred[3][tid];
    mu[tid] = m;
    var[tid] = fmaxf(dsum * (1.0f / 512.0f) - m * m, EPS);
  }
  __syncthreads();

  int cell = g * 256 + tid;
  int dd = cell >> 6, e = cell & 63;
  float csum = 0.f;
#pragma unroll 4
  for (int s = 0; s < 64; ++s) csum += covp[(size_t)(b * 64 + s) * 4096 + cell];
  float cov = csum * (1.0f / 512.0f) - mu[dd] * mu[e];
  float psum = 0.f;
  if (e != dd) {
    float denom = fmaxf(sqrtf(var[dd] * var[e]), EPS);
    psum = fabsf(fminf(fmaxf(cov / denom, -1.0f), 1.0f));
  }
  psum = wave_sum(psum);
  if ((tid & 63) == 0) phired[tid >> 6] = psum;
  __syncthreads();
  if (tid == 0) {
    atomicAdd(&out[B_ * T_ * D_ + b],
              (phired[0] + phired[1] + phired[2] + phired[3]) * (1.0f / 4096.0f));
    if (g == 0) {
      float ks = 0.f;
#pragma unroll
      for (int s = 0; s < 64; ++s) ks += kappap[b * 64 + s];
      out[B_ * T_ * D_ + B_ + b] = ks * (1.0f / 512.0f);
    }
  }
}

extern "C" void kernel_launch(void* const* d_in, const int* in_sizes, int n_in,
                              void* d_out, int out_size, void* d_ws, size_t ws_size,
                              hipStream_t stream) {
  const float* x0 = (const float*)d_in[0];
  const float* rs = (const float*)d_in[1];
  float* out = (float*)d_out;
  float* s0    = (float*)d_ws;                 // 131072 floats
  float* s1    = s0 + B_ * T_ * D_;            // 131072
  float* x1    = s1 + B_ * T_ * D_;            // 131072
  float* covp  = x1 + B_ * T_ * D_;            // 256*4096 = 1048576
  float* meanp = covp + 256 * 4096;            // 256*64
  float* diagp = meanp + 256 * 64;             // 256*64
  float* kappap = diagp + 256 * 64;            // 256

  dim3 fgrd(64, 4);
  proj_kernel<<<(B_ * T_) / 4, 256, 0, stream>>>(x0, s0);
  fiter_kernel<1, 0><<<fgrd, 512, 0, stream>>>(s0, x0, rs, x1, s1, (float*)0,
                                               (float*)0, (float*)0, (float*)0);
  fiter_kernel<0, 1><<<fgrd, 512, 0, stream>>>(s1, x1, rs, out, (float*)0,
                                               covp, meanp, diagp, kappap);
  finalize_kernel<<<dim3(16, B_), 256, 0, stream>>>(covp, meanp, diagp, kappap,
                                                    out);
}